// Round 4
// baseline (458.770 us; speedup 1.0000x reference)
//
#include <hip/hip_runtime.h>
#include <hip/hip_bf16.h>
#include <math.h>

#define BB 64
#define NN 320
#define NT 256
#define NV 32
#define NA 32
#define HIDD 512
#define NHEAD 8
#define FD 64

typedef __attribute__((ext_vector_type(8))) short bf16x8;
typedef __attribute__((ext_vector_type(4))) float floatx4;

// ---------------------------------------------------------------------------
// device-global scratch (stream-ordered producer->consumer, ~95 MB total):
//   me_g   : adj-masked exp(edge_logits), built once
//   fif/fjf: per-(b,head) attention dot products, written by gemm_h epilogue
//   ti/vi/ac planes: presplit input modalities (split-bf16, K padded to x64)
//   x planes: node features between layers (split-bf16 row-major [20480][512])
//   bw planes: current weight matrix in MFMA B-fragment layout
// Ht (fragment-layout H for attn) lives in d_ws (42 MB, exactly fits).
// ---------------------------------------------------------------------------
__device__ float me_g[NN * NN];
__device__ float fif_g[512 * NN];
__device__ float fjf_g[512 * NN];
__device__ unsigned short tihi_g[16384 * 768];
__device__ unsigned short tilo_g[16384 * 768];
__device__ unsigned short vihi_g[2048 * 64];
__device__ unsigned short vilo_g[2048 * 64];
__device__ unsigned short achi_g[2048 * 128];
__device__ unsigned short aclo_g[2048 * 128];
__device__ unsigned short xhi_g[20480 * 512];
__device__ unsigned short xlo_g[20480 * 512];
__device__ unsigned short bwhi_g[512 * 768];
__device__ unsigned short bwlo_g[512 * 768];

__device__ __forceinline__ void split1(float v, unsigned short& h, unsigned short& l) {
    unsigned u = __float_as_uint(v);
    unsigned hu = u & 0xFFFF0000u;
    float lf = v - __uint_as_float(hu);
    h = (unsigned short)(hu >> 16);
    l = (unsigned short)(__float_as_uint(lf) >> 16);
}
__device__ __forceinline__ unsigned pack2(unsigned short a, unsigned short b) {
    return (unsigned)a | ((unsigned)b << 16);
}

// ---------------------------------------------------------------------------
// me = adj ? exp(elog) : 0   (102400 elems, float4 per thread)
// ---------------------------------------------------------------------------
__global__ __launch_bounds__(256) void build_me(
    const int* __restrict__ adj, const float* __restrict__ elog)
{
    const int i4 = (blockIdx.x * 256 + threadIdx.x) * 4;
    const int4   a = *(const int4*)&adj[i4];
    const float4 e = *(const float4*)&elog[i4];
    float4 m;
    m.x = a.x ? __expf(e.x) : 0.f;
    m.y = a.y ? __expf(e.y) : 0.f;
    m.z = a.z ? __expf(e.z) : 0.f;
    m.w = a.w ? __expf(e.w) : 0.f;
    *(float4*)&me_g[i4] = m;
}

// ---------------------------------------------------------------------------
// presplit_A: fp32 [M][K] -> split-bf16 planes [M][Kp] (zero-padded cols).
// sel: 0=text, 1=visual, 2=acoustic. 4 elems/thread; vector path when K%4==0.
// ---------------------------------------------------------------------------
__global__ __launch_bounds__(256) void presplit_A(
    const float* __restrict__ src, int M, int K, int Kp, int sel)
{
    unsigned short* dh = (sel == 0) ? tihi_g : (sel == 1) ? vihi_g : achi_g;
    unsigned short* dl = (sel == 0) ? tilo_g : (sel == 1) ? vilo_g : aclo_g;
    const long long i4 = ((long long)blockIdx.x * 256 + threadIdx.x) * 4;
    if (i4 >= (long long)M * Kp) return;
    const int row = (int)(i4 / Kp);
    const int k = (int)(i4 - (long long)row * Kp);
    float v[4];
    if (((K & 3) == 0) && (k + 4 <= K)) {
        const float4 f = *(const float4*)&src[(size_t)row * K + k];
        v[0] = f.x; v[1] = f.y; v[2] = f.z; v[3] = f.w;
    } else {
#pragma unroll
        for (int e = 0; e < 4; e++) v[e] = (k + e < K) ? src[(size_t)row * K + k + e] : 0.f;
    }
    unsigned short h[4], l[4];
#pragma unroll
    for (int e = 0; e < 4; e++) split1(v[e], h[e], l[e]);
    *(uint2*)&dh[i4] = make_uint2(pack2(h[0], h[1]), pack2(h[2], h[3]));
    *(uint2*)&dl[i4] = make_uint2(pack2(l[0], l[1]), pack2(l[2], l[3]));
}

// ---------------------------------------------------------------------------
// presplit_B: weight fp32 -> split-bf16 in MFMA B-fragment layout:
//   bw[nt][kt][lane][e]  with col = nt*16+(lane&15), k = kt*32+(lane>>4)*8+e.
// wg_mode 0: W is [K][512] row-major (Wt/Wv/Wa).
// wg_mode 1: W is Wg_l [head][512][64]; col n -> head=n>>6, f=n&63.
// Zero-pads k >= K. grid (32, Kp/32) x 64 threads.
// ---------------------------------------------------------------------------
__global__ __launch_bounds__(64) void presplit_B(
    const float* __restrict__ W, int K, int Kp, int wg_mode)
{
    const int lane = threadIdx.x;
    const int nt = blockIdx.x, kt = blockIdx.y;
    const int col = nt * 16 + (lane & 15);
    const int k0 = kt * 32 + (lane >> 4) * 8;
    unsigned short h[8], l[8];
#pragma unroll
    for (int e = 0; e < 8; e++) {
        const int k = k0 + e;
        float v = 0.f;
        if (k < K) v = wg_mode ? W[(size_t)(col >> 6) * (512 * 64) + (size_t)k * 64 + (col & 63)]
                               : W[(size_t)k * 512 + col];
        split1(v, h[e], l[e]);
    }
    const size_t o = (((size_t)nt * (Kp >> 5) + kt) * 64 + lane) * 8;
    *(uint4*)&bwhi_g[o] = make_uint4(pack2(h[0], h[1]), pack2(h[2], h[3]),
                                     pack2(h[4], h[5]), pack2(h[6], h[7]));
    *(uint4*)&bwlo_g[o] = make_uint4(pack2(l[0], l[1]), pack2(l[2], l[3]),
                                     pack2(l[4], l[5]), pack2(l[6], l[7]));
}

// ---------------------------------------------------------------------------
// gemm_reg: zero-LDS, zero-barrier register GEMM. C[M,512]=A[M,Kp]@B[Kp,512],
// 3-pass split-bf16. 128x128 block tile, 4 waves each 64x64. Fragments loaded
// per-lane directly from global (L2/L3-resident planes):
//   A: row-major planes; lanes {l,l+16,l+32,l+48} cover full 64B lines.
//   B: fragment-layout planes; lane*16B contiguous per fragment.
// a_sel: 0=ti, 1=vi, 2=ac, 3=x. b_mode 0: proj -> write x split-planes with
// batch/node remap. b_mode 1: gemm_h -> Ht fragment epilogue + fi/fj fold.
// ---------------------------------------------------------------------------
__global__ __launch_bounds__(256, 3) void gemm_reg(
    unsigned short* __restrict__ Hthi, unsigned short* __restrict__ Htlo,
    const float* __restrict__ asrc, const float* __restrict__ adst,
    int Kp, int a_sel, int b_mode, int rpb, int noff)
{
    const unsigned short* Ahi = (a_sel == 0) ? tihi_g : (a_sel == 1) ? vihi_g
                              : (a_sel == 2) ? achi_g : xhi_g;
    const unsigned short* Alo = (a_sel == 0) ? tilo_g : (a_sel == 1) ? vilo_g
                              : (a_sel == 2) ? aclo_g : xlo_g;

    const int tid = threadIdx.x, lane = tid & 63, w = tid >> 6;
    const int rw = w >> 1, cw = w & 1;
    const int m0 = blockIdx.x * 128, n0 = blockIdx.y * 128;
    const int nk = Kp >> 5;

    floatx4 acc[4][4];
#pragma unroll
    for (int s = 0; s < 4; s++)
#pragma unroll
        for (int t = 0; t < 4; t++) acc[s][t] = (floatx4)0.f;

    const unsigned abase = (unsigned)(m0 + rw * 64 + (lane & 15)) * Kp + ((lane >> 4) << 3);
    const unsigned tgb = blockIdx.y * 8 + cw * 4;
    const unsigned bbase = (tgb * (unsigned)nk * 64 + lane) * 8;

    for (int kt = 0; kt < nk; kt++) {
        bf16x8 a_h[4], a_l[4], b_h[4], b_l[4];
#pragma unroll
        for (int s = 0; s < 4; s++) {
            const unsigned ao = abase + (unsigned)s * 16 * Kp + (unsigned)kt * 32;
            a_h[s] = *(const bf16x8*)&Ahi[ao];
            a_l[s] = *(const bf16x8*)&Alo[ao];
        }
#pragma unroll
        for (int t = 0; t < 4; t++) {
            const unsigned bo = bbase + ((unsigned)t * nk + kt) * 512;
            b_h[t] = *(const bf16x8*)&bwhi_g[bo];
            b_l[t] = *(const bf16x8*)&bwlo_g[bo];
        }
#pragma unroll
        for (int s = 0; s < 4; s++)
#pragma unroll
            for (int t = 0; t < 4; t++) {
                acc[s][t] = __builtin_amdgcn_mfma_f32_16x16x32_bf16(a_h[s], b_h[t], acc[s][t], 0, 0, 0);
                acc[s][t] = __builtin_amdgcn_mfma_f32_16x16x32_bf16(a_h[s], b_l[t], acc[s][t], 0, 0, 0);
                acc[s][t] = __builtin_amdgcn_mfma_f32_16x16x32_bf16(a_l[s], b_h[t], acc[s][t], 0, 0, 0);
            }
    }

    if (b_mode == 0) {
        // proj epilogue: write x as split-bf16 row-major planes with remap
        const int fq = lane & 15;
#pragma unroll
        for (int s = 0; s < 4; s++) {
            const int gr0 = m0 + rw * 64 + s * 16 + (lane >> 4) * 4;
#pragma unroll
            for (int r = 0; r < 4; r++) {
                const unsigned grow = gr0 + r;
                const unsigned b = grow / (unsigned)rpb;
                const unsigned rr = grow - b * rpb;
                const size_t ro = ((size_t)b * NN + noff + rr) * HIDD + n0 + cw * 64 + fq;
#pragma unroll
                for (int t = 0; t < 4; t++) {
                    unsigned short h, l; split1(acc[s][t][r], h, l);
                    xhi_g[ro + t * 16] = h;
                    xlo_g[ro + t * 16] = l;
                }
            }
        }
    } else {
        // Ht fragment-layout split-bf16 epilogue
        const int hd = (n0 + cw * 64) >> 6;
        const int fq = lane & 15;
#pragma unroll
        for (int s = 0; s < 4; s++) {
            const int m_s = m0 + rw * 64 + s * 16 + (lane >> 4) * 4;  // rows m_s..m_s+3
            const unsigned b = (unsigned)m_s / 320u;   // constant over r (m_s%4==0)
            const int jb = m_s - b * 320;              // node j base, mult of 4
            const int ks = jb >> 5;
            const int jg2 = (jb >> 3) & 3;
            const int eb = jb & 7;                     // 0 or 4
            const size_t slab = (size_t)b * 8 + hd;
#pragma unroll
            for (int t = 0; t < 4; t++) {
                unsigned short h0,h1,h2,h3,l0,l1,l2,l3;
                split1(acc[s][t][0],h0,l0); split1(acc[s][t][1],h1,l1);
                split1(acc[s][t][2],h2,l2); split1(acc[s][t][3],h3,l3);
                const size_t base = (((slab * 10 + ks) * 4 + t) * 512
                                     + (size_t)(fq | (jg2 << 4)) * 8) + eb;
                *(uint2*)&Hthi[base] = make_uint2(pack2(h0,h1), pack2(h2,h3));
                *(uint2*)&Htlo[base] = make_uint2(pack2(l0,l1), pack2(l2,l3));
            }
        }
        // fi/fj fold: exact fp32 dot(H_row, a_src/a_dst) per (row, head)
        float as4[4], ad4[4];
#pragma unroll
        for (int t = 0; t < 4; t++) {
            as4[t] = asrc[hd * 64 + t * 16 + fq];
            ad4[t] = adst[hd * 64 + t * 16 + fq];
        }
#pragma unroll
        for (int s = 0; s < 4; s++) {
            const int m_s = m0 + rw * 64 + s * 16 + (lane >> 4) * 4;
            const unsigned b = (unsigned)m_s / 320u;
            const int jb = m_s - b * 320;
            float4 fi4, fj4;
#pragma unroll
            for (int r = 0; r < 4; r++) {
                float fi = (acc[s][0][r]*as4[0] + acc[s][1][r]*as4[1])
                         + (acc[s][2][r]*as4[2] + acc[s][3][r]*as4[3]);
                float fj = (acc[s][0][r]*ad4[0] + acc[s][1][r]*ad4[1])
                         + (acc[s][2][r]*ad4[2] + acc[s][3][r]*ad4[3]);
#pragma unroll
                for (int d = 1; d < 16; d <<= 1) {
                    fi += __shfl_xor(fi, d);
                    fj += __shfl_xor(fj, d);
                }
                ((float*)&fi4)[r] = fi; ((float*)&fj4)[r] = fj;
            }
            if (fq == 0) {
                const size_t o = ((size_t)b * 8 + hd) * NN + jb;
                *(float4*)&fif_g[o] = fi4;
                *(float4*)&fjf_g[o] = fj4;
            }
        }
    }
}

// ---------------------------------------------------------------------------
// MFMA GAT attention (v4 structure): grid (512, 2), 4 blocks/CU.
// block-y splits i: y=0 owns ip {0,1,2}, y=1 owns {3,4}. fi/fj precomputed
// by gemm_h; scores use me = adj?exp(elog):0. Zero barriers/atomics in main
// loop. final_out=0 (layer 0): apply elu, write split-bf16 x planes.
// final_out=1 (layer 1): write fp32 to d_out.
// ---------------------------------------------------------------------------
template<int IP0, int NIP>
__device__ __forceinline__ void attn_body(
    const unsigned short* __restrict__ Hthi, const unsigned short* __restrict__ Htlo,
    float* __restrict__ xout, int final_out, float* fjs, float* ls)
{
    const int bh = blockIdx.x;          // b*8 + hd
    const int hd = bh & 7, b = bh >> 3;
    const int tid = threadIdx.x, lane = tid & 63, w = tid >> 6;
    const int fq = lane & 15, jg = lane >> 4;

    for (int r = tid; r < NN; r += 256) fjs[r] = fjf_g[bh * NN + r];

    float fir[NIP];
#pragma unroll
    for (int ip = 0; ip < NIP; ip++)
        fir[ip] = fif_g[bh * NN + (IP0 + ip) * 64 + (w << 4) + fq];
    __syncthreads();

    floatx4 acc[NIP][4];
#pragma unroll
    for (int ip = 0; ip < NIP; ip++)
#pragma unroll
        for (int nt = 0; nt < 4; nt++) acc[ip][nt] = (floatx4)0.f;
    float lacc[NIP];
#pragma unroll
    for (int ip = 0; ip < NIP; ip++) lacc[ip] = 0.f;

    for (int ks = 0; ks < 10; ks++) {
        const int j8 = ks * 32 + jg * 8;
        const float4 fj0 = *(const float4*)&fjs[j8];
        const float4 fj1 = *(const float4*)&fjs[j8 + 4];

        // ---- phase 1: scores -> exp*me -> split-bf16 A-frags ----
        bf16x8 ahh[NIP], all[NIP];
#pragma unroll
        for (int ip = 0; ip < NIP; ip++) {
            const int i = (IP0 + ip) * 64 + (w << 4) + fq;
            const float fiv = fir[ip];
            const unsigned g = (unsigned)i * NN + j8;
            const float4 m0 = *(const float4*)&me_g[g];
            const float4 m1 = *(const float4*)&me_g[g + 4];
            float p[8];
            {
                float s;
                s = fiv + fj0.x; s = fmaxf(s, 0.2f*s); p[0] = __expf(s) * m0.x;
                s = fiv + fj0.y; s = fmaxf(s, 0.2f*s); p[1] = __expf(s) * m0.y;
                s = fiv + fj0.z; s = fmaxf(s, 0.2f*s); p[2] = __expf(s) * m0.z;
                s = fiv + fj0.w; s = fmaxf(s, 0.2f*s); p[3] = __expf(s) * m0.w;
                s = fiv + fj1.x; s = fmaxf(s, 0.2f*s); p[4] = __expf(s) * m1.x;
                s = fiv + fj1.y; s = fmaxf(s, 0.2f*s); p[5] = __expf(s) * m1.y;
                s = fiv + fj1.z; s = fmaxf(s, 0.2f*s); p[6] = __expf(s) * m1.z;
                s = fiv + fj1.w; s = fmaxf(s, 0.2f*s); p[7] = __expf(s) * m1.w;
            }
            lacc[ip] += ((p[0]+p[1]) + (p[2]+p[3])) + ((p[4]+p[5]) + (p[6]+p[7]));

            unsigned short ph[8], pl[8];
#pragma unroll
            for (int e = 0; e < 8; e++) split1(p[e], ph[e], pl[e]);
            union { uint4 u; bf16x8 v; } ua, ul;
            ua.u = make_uint4(pack2(ph[0],ph[1]), pack2(ph[2],ph[3]),
                              pack2(ph[4],ph[5]), pack2(ph[6],ph[7]));
            ul.u = make_uint4(pack2(pl[0],pl[1]), pack2(pl[2],pl[3]),
                              pack2(pl[4],pl[5]), pack2(pl[6],pl[7]));
            ahh[ip] = ua.v; all[ip] = ul.v;
        }

        // ---- phase 2: per f-tile, load B pair then 3*NIP MFMAs ----
#pragma unroll
        for (int nt = 0; nt < 4; nt++) {
            const unsigned off = (((unsigned)bh * 10 + ks) * 4 + nt) * 512 + (unsigned)lane * 8;
            const bf16x8 bhf = *(const bf16x8*)&Hthi[off];
            const bf16x8 blf = *(const bf16x8*)&Htlo[off];
#pragma unroll
            for (int ip = 0; ip < NIP; ip++) {
                acc[ip][nt] = __builtin_amdgcn_mfma_f32_16x16x32_bf16(ahh[ip], bhf, acc[ip][nt], 0, 0, 0);
                acc[ip][nt] = __builtin_amdgcn_mfma_f32_16x16x32_bf16(ahh[ip], blf, acc[ip][nt], 0, 0, 0);
                acc[ip][nt] = __builtin_amdgcn_mfma_f32_16x16x32_bf16(all[ip], bhf, acc[ip][nt], 0, 0, 0);
            }
        }
    }

    // ---- l reduction: sum over the 4 jg lanes holding the same i ----
#pragma unroll
    for (int ip = 0; ip < NIP; ip++) {
        float l = lacc[ip];
        l += __shfl_xor(l, 16);
        l += __shfl_xor(l, 32);
        if (jg == 0) ls[(IP0 + ip) * 64 + (w << 4) + fq] = l;
    }
    __syncthreads();

    // ---- epilogue: D col(f)=lane&15, row(i)=(lane>>4)*4+reg ----
#pragma unroll
    for (int ip = 0; ip < NIP; ip++) {
        const int ib = ((IP0 + ip) * 4 + w) * 16 + jg * 4;
#pragma unroll
        for (int r = 0; r < 4; r++) {
            const float lv = ls[ib + r];
            const float inv = (lv > 0.f) ? 1.f / lv : 0.f;   // fully-masked row -> 0
            const size_t ro = ((size_t)(b * NN + ib + r)) * HIDD + hd * 64;
            if (final_out) {
#pragma unroll
                for (int nt = 0; nt < 4; nt++)
                    xout[ro + nt * 16 + fq] = acc[ip][nt][r] * inv;
            } else {
#pragma unroll
                for (int nt = 0; nt < 4; nt++) {
                    float vv = acc[ip][nt][r] * inv;
                    vv = (vv > 0.f) ? vv : __expf(vv) - 1.f;   // elu
                    unsigned short h, l2; split1(vv, h, l2);
                    xhi_g[ro + nt * 16 + fq] = h;
                    xlo_g[ro + nt * 16 + fq] = l2;
                }
            }
        }
    }
}

__global__ __launch_bounds__(256, 4) void attn_mfma(
    const unsigned short* __restrict__ Hthi, const unsigned short* __restrict__ Htlo,
    float* __restrict__ xout, int final_out)
{
    __shared__ float fjs[NN];
    __shared__ float ls[NN];
    if (blockIdx.y == 0) attn_body<0, 3>(Hthi, Htlo, xout, final_out, fjs, ls);
    else                 attn_body<3, 2>(Hthi, Htlo, xout, final_out, fjs, ls);
}

// ---------------------------------------------------------------------------
// Flow: build_me; presplit inputs; per matmul: presplit_B then gemm_reg.
// proj -> x planes (globals); per layer: gemm_h -> Ht(ws)+fi/fj;
// attn -> x planes (l=0, elu) / fp32 d_out (l=1). Strictly stream-ordered.
// ---------------------------------------------------------------------------
extern "C" void kernel_launch(void* const* d_in, const int* in_sizes, int n_in,
                              void* d_out, int out_size, void* d_ws, size_t ws_size,
                              hipStream_t stream)
{
    (void)in_sizes; (void)n_in; (void)out_size; (void)ws_size;
    const float* text     = (const float*)d_in[0];
    const float* visual   = (const float*)d_in[1];
    const float* acoustic = (const float*)d_in[2];
    const int*   adj      = (const int*)d_in[3];
    const float* Wt       = (const float*)d_in[4];
    const float* Wv       = (const float*)d_in[5];
    const float* Wa       = (const float*)d_in[6];
    const float* Wg       = (const float*)d_in[7];
    const float* a_src    = (const float*)d_in[8];
    const float* a_dst    = (const float*)d_in[9];
    const float* elog     = (const float*)d_in[10];

    float* xbuf = (float*)d_out;
    unsigned short* Hthi = (unsigned short*)d_ws;
    unsigned short* Htlo = Hthi + (size_t)512 * 10 * 4 * 512;   // 10,485,760 shorts

    build_me<<<NN * NN / 1024, 256, 0, stream>>>(adj, elog);

    presplit_A<<<(16384 * 768) / 1024, 256, 0, stream>>>(text,     16384, 768, 768, 0);
    presplit_A<<<(2048 * 64)   / 1024, 256, 0, stream>>>(visual,   2048,  47,  64,  1);
    presplit_A<<<(2048 * 128)  / 1024, 256, 0, stream>>>(acoustic, 2048,  74,  128, 2);

    // projections -> x planes
    presplit_B<<<dim3(32, 768 / 32), 64, 0, stream>>>(Wt, 768, 768, 0);
    gemm_reg<<<dim3((BB*NT)/128, 4), 256, 0, stream>>>(nullptr, nullptr, nullptr, nullptr,
                                                       768, 0, 0, NT, 0);
    presplit_B<<<dim3(32, 64 / 32), 64, 0, stream>>>(Wv, 47, 64, 0);
    gemm_reg<<<dim3((BB*NV)/128, 4), 256, 0, stream>>>(nullptr, nullptr, nullptr, nullptr,
                                                       64, 1, 0, NV, NT);
    presplit_B<<<dim3(32, 128 / 32), 64, 0, stream>>>(Wa, 74, 128, 0);
    gemm_reg<<<dim3((BB*NA)/128, 4), 256, 0, stream>>>(nullptr, nullptr, nullptr, nullptr,
                                                       128, 2, 0, NA, NT + NV);

    for (int l = 0; l < 2; l++) {
        const float* Wg_l = Wg + (size_t)l * NHEAD * HIDD * FD;
        presplit_B<<<dim3(32, 512 / 32), 64, 0, stream>>>(Wg_l, 512, 512, 1);
        gemm_reg<<<dim3((BB*NN)/128, 4), 256, 0, stream>>>(Hthi, Htlo,
            a_src + l * NHEAD * FD, a_dst + l * NHEAD * FD, 512, 3, 1, NN, 0);
        attn_mfma<<<dim3(BB * NHEAD, 2), 256, 0, stream>>>(
            Hthi, Htlo, xbuf, (l == 0) ? 0 : 1);
    }
}

// Round 5
// 367.818 us; speedup vs baseline: 1.2473x; 1.2473x over previous
//
#include <hip/hip_runtime.h>
#include <hip/hip_bf16.h>
#include <math.h>

#define BB 64
#define NN 320
#define NT 256
#define NV 32
#define NA 32
#define HIDD 512
#define NHEAD 8
#define FD 64

typedef __attribute__((ext_vector_type(8))) short bf16x8;
typedef __attribute__((ext_vector_type(4))) float floatx4;

// ---------------------------------------------------------------------------
// device-global scratch (stream-ordered producer->consumer):
//   me_g   : adj-masked exp(edge_logits), built once
//   fif/fjf: per-(b,head) attention dot products, written by gemm_h epilogue
//   ti/vi/ac planes: presplit inputs, A-FRAGMENT layout [g][kt][lane][8]
//     (g = row/16, kt = k/32, lane = (row&15)|(((k>>3)&3)<<4), e = k&7)
//   x planes: node features between layers, same A-fragment layout (nk=16)
//   bw planes: current weight matrix, B-fragment layout [tg][kt][lane][8]
// Every GEMM load is lane-contiguous 16B (1KB/instruction). Ht in d_ws.
// ---------------------------------------------------------------------------
__device__ float me_g[NN * NN];
__device__ float fif_g[512 * NN];
__device__ float fjf_g[512 * NN];
__device__ unsigned short tihi_g[16384 * 768];
__device__ unsigned short tilo_g[16384 * 768];
__device__ unsigned short vihi_g[2048 * 64];
__device__ unsigned short vilo_g[2048 * 64];
__device__ unsigned short achi_g[2048 * 128];
__device__ unsigned short aclo_g[2048 * 128];
__device__ unsigned short xhi_g[20480 * 512];
__device__ unsigned short xlo_g[20480 * 512];
__device__ unsigned short bwhi_g[512 * 768];
__device__ unsigned short bwlo_g[512 * 768];

__device__ __forceinline__ void split1(float v, unsigned short& h, unsigned short& l) {
    unsigned u = __float_as_uint(v);
    unsigned hu = u & 0xFFFF0000u;
    float lf = v - __uint_as_float(hu);
    h = (unsigned short)(hu >> 16);
    l = (unsigned short)(__float_as_uint(lf) >> 16);
}
__device__ __forceinline__ unsigned pack2(unsigned short a, unsigned short b) {
    return (unsigned)a | ((unsigned)b << 16);
}

// ---------------------------------------------------------------------------
// me = adj ? exp(elog) : 0
// ---------------------------------------------------------------------------
__global__ __launch_bounds__(256) void build_me(
    const int* __restrict__ adj, const float* __restrict__ elog)
{
    const int i4 = (blockIdx.x * 256 + threadIdx.x) * 4;
    const int4   a = *(const int4*)&adj[i4];
    const float4 e = *(const float4*)&elog[i4];
    float4 m;
    m.x = a.x ? __expf(e.x) : 0.f;
    m.y = a.y ? __expf(e.y) : 0.f;
    m.z = a.z ? __expf(e.z) : 0.f;
    m.w = a.w ? __expf(e.w) : 0.f;
    *(float4*)&me_g[i4] = m;
}

// ---------------------------------------------------------------------------
// presplit_A: fp32 [M][K] -> split-bf16 A-fragment planes [M/16][nk][64][8].
// Thread t handles record element (rec=t>>6, lane=t&63): row=g*16+(lane&15),
// k0=kt*32+((lane>>4)<<3). Reads are 32B/row-chunk (full 64B lines across the
// wave); writes are perfectly coalesced (dst offset = t*8 shorts).
// ---------------------------------------------------------------------------
__global__ __launch_bounds__(256) void presplit_A(
    const float* __restrict__ src, int M, int K, int nk, int sel)
{
    unsigned short* dh = (sel == 0) ? tihi_g : (sel == 1) ? vihi_g : achi_g;
    unsigned short* dl = (sel == 0) ? tilo_g : (sel == 1) ? vilo_g : aclo_g;
    const unsigned t = blockIdx.x * 256 + threadIdx.x;
    const unsigned lane = t & 63, rec = t >> 6;
    const unsigned kt = rec % (unsigned)nk, g = rec / (unsigned)nk;
    const int row = g * 16 + (lane & 15);
    if (row >= M) return;
    const int k0 = kt * 32 + ((lane >> 4) << 3);
    float v[8];
    if (((K & 3) == 0) && (k0 + 8 <= K)) {
        *(float4*)&v[0] = *(const float4*)&src[(size_t)row * K + k0];
        *(float4*)&v[4] = *(const float4*)&src[(size_t)row * K + k0 + 4];
    } else {
#pragma unroll
        for (int e = 0; e < 8; e++) v[e] = (k0 + e < K) ? src[(size_t)row * K + k0 + e] : 0.f;
    }
    unsigned short h[8], l[8];
#pragma unroll
    for (int e = 0; e < 8; e++) split1(v[e], h[e], l[e]);
    const size_t o = (size_t)t * 8;
    *(uint4*)&dh[o] = make_uint4(pack2(h[0],h[1]), pack2(h[2],h[3]),
                                 pack2(h[4],h[5]), pack2(h[6],h[7]));
    *(uint4*)&dl[o] = make_uint4(pack2(l[0],l[1]), pack2(l[2],l[3]),
                                 pack2(l[4],l[5]), pack2(l[6],l[7]));
}

// ---------------------------------------------------------------------------
// presplit_B: weight fp32 -> split-bf16 B-fragment planes [tg][kt][64][8]:
//   col = tg*16+(lane&15), k = kt*32+(lane>>4)*8+e. Zero-pads k >= K.
// wg_mode 0: W row-major [K][512]. wg_mode 1: W = Wg_l [head][512][64].
// ---------------------------------------------------------------------------
__global__ __launch_bounds__(64) void presplit_B(
    const float* __restrict__ W, int K, int Kp, int wg_mode)
{
    const int lane = threadIdx.x;
    const int nt = blockIdx.x, kt = blockIdx.y;
    const int col = nt * 16 + (lane & 15);
    const int k0 = kt * 32 + (lane >> 4) * 8;
    unsigned short h[8], l[8];
#pragma unroll
    for (int e = 0; e < 8; e++) {
        const int k = k0 + e;
        float v = 0.f;
        if (k < K) v = wg_mode ? W[(size_t)(col >> 6) * (512 * 64) + (size_t)k * 64 + (col & 63)]
                               : W[(size_t)k * 512 + col];
        split1(v, h[e], l[e]);
    }
    const size_t o = (((size_t)nt * (Kp >> 5) + kt) * 64 + lane) * 8;
    *(uint4*)&bwhi_g[o] = make_uint4(pack2(h[0], h[1]), pack2(h[2], h[3]),
                                     pack2(h[4], h[5]), pack2(h[6], h[7]));
    *(uint4*)&bwlo_g[o] = make_uint4(pack2(l[0], l[1]), pack2(l[2], l[3]),
                                     pack2(l[4], l[5]), pack2(l[6], l[7]));
}

// ---------------------------------------------------------------------------
// gemm_reg v2: zero-LDS-mainloop register GEMM, A and B both fragment-layout
// (all loads lane-contiguous 16B), even/odd register double-buffer over kt
// so next-kt loads are in flight during current-kt MFMAs.
// 128x128 tile, 4 waves each 64x64, 3-pass split-bf16.
// b_mode 0: proj epilogue -> x fragment planes via per-wave LDS transpose
//           (16x68-padded fp32 slab; 2-way max bank aliasing = free).
// b_mode 1: gemm_h -> Ht fragment epilogue + fi/fj fold.
// ---------------------------------------------------------------------------
#define GLOAD(AH, AL, BH, BL, KT)                                              \
  { _Pragma("unroll") for (int s = 0; s < 4; s++) {                            \
      const unsigned ao = ((gbase + s) * (unsigned)nk + (KT)) * 512 + la8;     \
      AH[s] = *(const bf16x8*)&Ahi[ao];                                        \
      AL[s] = *(const bf16x8*)&Alo[ao]; }                                      \
    _Pragma("unroll") for (int t = 0; t < 4; t++) {                            \
      const unsigned bo = ((tgb + t) * (unsigned)nk + (KT)) * 512 + la8;       \
      BH[t] = *(const bf16x8*)&bwhi_g[bo];                                     \
      BL[t] = *(const bf16x8*)&bwlo_g[bo]; } }

#define GMFMA(AH, AL, BH, BL)                                                  \
  _Pragma("unroll") for (int s = 0; s < 4; s++)                                \
  _Pragma("unroll") for (int t = 0; t < 4; t++) {                              \
      acc[s][t] = __builtin_amdgcn_mfma_f32_16x16x32_bf16(AH[s], BH[t], acc[s][t], 0, 0, 0); \
      acc[s][t] = __builtin_amdgcn_mfma_f32_16x16x32_bf16(AH[s], BL[t], acc[s][t], 0, 0, 0); \
      acc[s][t] = __builtin_amdgcn_mfma_f32_16x16x32_bf16(AL[s], BH[t], acc[s][t], 0, 0, 0); }

__global__ __launch_bounds__(256, 2) void gemm_reg(
    unsigned short* __restrict__ Hthi, unsigned short* __restrict__ Htlo,
    const float* __restrict__ asrc, const float* __restrict__ adst,
    int nk, int a_sel, int b_mode, int rpb, int noff)
{
    __shared__ float slab[4][16][68];   // per-wave transpose slab (epilogue)

    const unsigned short* Ahi = (a_sel == 0) ? tihi_g : (a_sel == 1) ? vihi_g
                              : (a_sel == 2) ? achi_g : xhi_g;
    const unsigned short* Alo = (a_sel == 0) ? tilo_g : (a_sel == 1) ? vilo_g
                              : (a_sel == 2) ? aclo_g : xlo_g;

    const int tid = threadIdx.x, lane = tid & 63, w = tid >> 6;
    const int rw = w >> 1, cw = w & 1;
    const int m0 = blockIdx.x * 128, n0 = blockIdx.y * 128;
    const unsigned gbase = (unsigned)(m0 >> 4) + rw * 4;   // A 16-row group (+s)
    const unsigned tgb   = (unsigned)(n0 >> 4) + cw * 4;   // B 16-col group (+t)
    const unsigned la8   = (unsigned)lane * 8;

    floatx4 acc[4][4];
#pragma unroll
    for (int s = 0; s < 4; s++)
#pragma unroll
        for (int t = 0; t < 4; t++) acc[s][t] = (floatx4)0.f;

    bf16x8 ahE[4], alE[4], bhE[4], blE[4];
    bf16x8 ahO[4], alO[4], bhO[4], blO[4];

    GLOAD(ahE, alE, bhE, blE, 0u);
    for (int kt = 0; kt < nk; kt += 2) {          // nk is even for all calls
        GLOAD(ahO, alO, bhO, blO, (unsigned)(kt + 1));
        GMFMA(ahE, alE, bhE, blE);
        if (kt + 2 < nk) GLOAD(ahE, alE, bhE, blE, (unsigned)(kt + 2));
        GMFMA(ahO, alO, bhO, blO);
    }

    const int fq = lane & 15, rl = lane >> 4;

    if (b_mode == 0) {
        // ---- proj epilogue: D -> x fragment planes via LDS transpose ----
        float (*sl)[68] = slab[w];
        const int ktg0 = (n0 + cw * 64) >> 5;     // x k-tile base (x nk = 16)
#pragma unroll
        for (int s = 0; s < 4; s++) {
#pragma unroll
            for (int t = 0; t < 4; t++)
#pragma unroll
                for (int r = 0; r < 4; r++)
                    sl[rl * 4 + r][t * 16 + fq] = acc[s][t][r];
            const int grow16 = m0 + rw * 64 + s * 16;
            const int b = grow16 / rpb;
            const int rr = grow16 - b * rpb;
            const unsigned g = (unsigned)b * 20 + (unsigned)((noff + rr) >> 4);
#pragma unroll
            for (int kth = 0; kth < 2; kth++) {
                float f[8];
                *(float4*)&f[0] = *(const float4*)&sl[fq][kth * 32 + rl * 8];
                *(float4*)&f[4] = *(const float4*)&sl[fq][kth * 32 + rl * 8 + 4];
                unsigned short h[8], l[8];
#pragma unroll
                for (int e = 0; e < 8; e++) split1(f[e], h[e], l[e]);
                const size_t o = (((size_t)g * 16 + ktg0 + kth) * 64 + lane) * 8;
                *(uint4*)&xhi_g[o] = make_uint4(pack2(h[0],h[1]), pack2(h[2],h[3]),
                                                pack2(h[4],h[5]), pack2(h[6],h[7]));
                *(uint4*)&xlo_g[o] = make_uint4(pack2(l[0],l[1]), pack2(l[2],l[3]),
                                                pack2(l[4],l[5]), pack2(l[6],l[7]));
            }
        }
    } else {
        // ---- Ht fragment-layout split-bf16 epilogue ----
        const int hd = (n0 + cw * 64) >> 6;
#pragma unroll
        for (int s = 0; s < 4; s++) {
            const int m_s = m0 + rw * 64 + s * 16 + rl * 4;   // rows m_s..m_s+3
            const unsigned b = (unsigned)m_s / 320u;
            const int jb = m_s - b * 320;
            const int ks = jb >> 5;
            const int jg2 = (jb >> 3) & 3;
            const int eb = jb & 7;
            const size_t slabo = (size_t)b * 8 + hd;
#pragma unroll
            for (int t = 0; t < 4; t++) {
                unsigned short h0,h1,h2,h3,l0,l1,l2,l3;
                split1(acc[s][t][0],h0,l0); split1(acc[s][t][1],h1,l1);
                split1(acc[s][t][2],h2,l2); split1(acc[s][t][3],h3,l3);
                const size_t base = (((slabo * 10 + ks) * 4 + t) * 512
                                     + (size_t)(fq | (jg2 << 4)) * 8) + eb;
                *(uint2*)&Hthi[base] = make_uint2(pack2(h0,h1), pack2(h2,h3));
                *(uint2*)&Htlo[base] = make_uint2(pack2(l0,l1), pack2(l2,l3));
            }
        }
        // fi/fj fold: exact fp32 dot(H_row, a_src/a_dst) per (row, head)
        float as4[4], ad4[4];
#pragma unroll
        for (int t = 0; t < 4; t++) {
            as4[t] = asrc[hd * 64 + t * 16 + fq];
            ad4[t] = adst[hd * 64 + t * 16 + fq];
        }
#pragma unroll
        for (int s = 0; s < 4; s++) {
            const int m_s = m0 + rw * 64 + s * 16 + rl * 4;
            const unsigned b = (unsigned)m_s / 320u;
            const int jb = m_s - b * 320;
            float4 fi4, fj4;
#pragma unroll
            for (int r = 0; r < 4; r++) {
                float fi = (acc[s][0][r]*as4[0] + acc[s][1][r]*as4[1])
                         + (acc[s][2][r]*as4[2] + acc[s][3][r]*as4[3]);
                float fj = (acc[s][0][r]*ad4[0] + acc[s][1][r]*ad4[1])
                         + (acc[s][2][r]*ad4[2] + acc[s][3][r]*ad4[3]);
#pragma unroll
                for (int d = 1; d < 16; d <<= 1) {
                    fi += __shfl_xor(fi, d);
                    fj += __shfl_xor(fj, d);
                }
                ((float*)&fi4)[r] = fi; ((float*)&fj4)[r] = fj;
            }
            if (fq == 0) {
                const size_t o = ((size_t)b * 8 + hd) * NN + jb;
                *(float4*)&fif_g[o] = fi4;
                *(float4*)&fjf_g[o] = fj4;
            }
        }
    }
}

// ---------------------------------------------------------------------------
// MFMA GAT attention (v4 structure): grid (512, 2), 4 blocks/CU.
// final_out=0 (layer 0): elu, write x fragment planes via LDS transpose.
// final_out=1 (layer 1): write fp32 to d_out.
// ---------------------------------------------------------------------------
template<int IP0, int NIP>
__device__ __forceinline__ void attn_body(
    const unsigned short* __restrict__ Hthi, const unsigned short* __restrict__ Htlo,
    float* __restrict__ xout, int final_out, float* fjs, float* ls,
    float (*slabA)[16][68])
{
    const int bh = blockIdx.x;          // b*8 + hd
    const int hd = bh & 7, b = bh >> 3;
    const int tid = threadIdx.x, lane = tid & 63, w = tid >> 6;
    const int fq = lane & 15, jg = lane >> 4;

    for (int r = tid; r < NN; r += 256) fjs[r] = fjf_g[bh * NN + r];

    float fir[NIP];
#pragma unroll
    for (int ip = 0; ip < NIP; ip++)
        fir[ip] = fif_g[bh * NN + (IP0 + ip) * 64 + (w << 4) + fq];
    __syncthreads();

    floatx4 acc[NIP][4];
#pragma unroll
    for (int ip = 0; ip < NIP; ip++)
#pragma unroll
        for (int nt = 0; nt < 4; nt++) acc[ip][nt] = (floatx4)0.f;
    float lacc[NIP];
#pragma unroll
    for (int ip = 0; ip < NIP; ip++) lacc[ip] = 0.f;

    for (int ks = 0; ks < 10; ks++) {
        const int j8 = ks * 32 + jg * 8;
        const float4 fj0 = *(const float4*)&fjs[j8];
        const float4 fj1 = *(const float4*)&fjs[j8 + 4];

        // ---- phase 1: scores -> exp*me -> split-bf16 A-frags ----
        bf16x8 ahh[NIP], all[NIP];
#pragma unroll
        for (int ip = 0; ip < NIP; ip++) {
            const int i = (IP0 + ip) * 64 + (w << 4) + fq;
            const float fiv = fir[ip];
            const unsigned g = (unsigned)i * NN + j8;
            const float4 m0 = *(const float4*)&me_g[g];
            const float4 m1 = *(const float4*)&me_g[g + 4];
            float p[8];
            {
                float s;
                s = fiv + fj0.x; s = fmaxf(s, 0.2f*s); p[0] = __expf(s) * m0.x;
                s = fiv + fj0.y; s = fmaxf(s, 0.2f*s); p[1] = __expf(s) * m0.y;
                s = fiv + fj0.z; s = fmaxf(s, 0.2f*s); p[2] = __expf(s) * m0.z;
                s = fiv + fj0.w; s = fmaxf(s, 0.2f*s); p[3] = __expf(s) * m0.w;
                s = fiv + fj1.x; s = fmaxf(s, 0.2f*s); p[4] = __expf(s) * m1.x;
                s = fiv + fj1.y; s = fmaxf(s, 0.2f*s); p[5] = __expf(s) * m1.y;
                s = fiv + fj1.z; s = fmaxf(s, 0.2f*s); p[6] = __expf(s) * m1.z;
                s = fiv + fj1.w; s = fmaxf(s, 0.2f*s); p[7] = __expf(s) * m1.w;
            }
            lacc[ip] += ((p[0]+p[1]) + (p[2]+p[3])) + ((p[4]+p[5]) + (p[6]+p[7]));

            unsigned short ph[8], pl[8];
#pragma unroll
            for (int e = 0; e < 8; e++) split1(p[e], ph[e], pl[e]);
            union { uint4 u; bf16x8 v; } ua, ul;
            ua.u = make_uint4(pack2(ph[0],ph[1]), pack2(ph[2],ph[3]),
                              pack2(ph[4],ph[5]), pack2(ph[6],ph[7]));
            ul.u = make_uint4(pack2(pl[0],pl[1]), pack2(pl[2],pl[3]),
                              pack2(pl[4],pl[5]), pack2(pl[6],pl[7]));
            ahh[ip] = ua.v; all[ip] = ul.v;
        }

        // ---- phase 2: per f-tile, load B pair then 3*NIP MFMAs ----
#pragma unroll
        for (int nt = 0; nt < 4; nt++) {
            const unsigned off = (((unsigned)bh * 10 + ks) * 4 + nt) * 512 + (unsigned)lane * 8;
            const bf16x8 bhf = *(const bf16x8*)&Hthi[off];
            const bf16x8 blf = *(const bf16x8*)&Htlo[off];
#pragma unroll
            for (int ip = 0; ip < NIP; ip++) {
                acc[ip][nt] = __builtin_amdgcn_mfma_f32_16x16x32_bf16(ahh[ip], bhf, acc[ip][nt], 0, 0, 0);
                acc[ip][nt] = __builtin_amdgcn_mfma_f32_16x16x32_bf16(ahh[ip], blf, acc[ip][nt], 0, 0, 0);
                acc[ip][nt] = __builtin_amdgcn_mfma_f32_16x16x32_bf16(all[ip], bhf, acc[ip][nt], 0, 0, 0);
            }
        }
    }

    // ---- l reduction: sum over the 4 jg lanes holding the same i ----
#pragma unroll
    for (int ip = 0; ip < NIP; ip++) {
        float l = lacc[ip];
        l += __shfl_xor(l, 16);
        l += __shfl_xor(l, 32);
        if (jg == 0) ls[(IP0 + ip) * 64 + (w << 4) + fq] = l;
    }
    __syncthreads();

    // ---- epilogue: D col(f)=fq, row(i)=jg*4+r ----
    if (final_out) {
#pragma unroll
        for (int ip = 0; ip < NIP; ip++) {
            const int ib = ((IP0 + ip) * 4 + w) * 16 + jg * 4;
#pragma unroll
            for (int r = 0; r < 4; r++) {
                const float lv = ls[ib + r];
                const float inv = (lv > 0.f) ? 1.f / lv : 0.f;
                const size_t ro = ((size_t)(b * NN + ib + r)) * HIDD + hd * 64;
#pragma unroll
                for (int nt = 0; nt < 4; nt++)
                    xout[ro + nt * 16 + fq] = acc[ip][nt][r] * inv;
            }
        }
    } else {
        // elu + write x fragment planes via per-wave LDS transpose
        float (*sl)[68] = slabA[w];
        const int ktg0 = hd * 2;
#pragma unroll
        for (int ip = 0; ip < NIP; ip++) {
            const int ib = ((IP0 + ip) * 4 + w) * 16 + jg * 4;
#pragma unroll
            for (int r = 0; r < 4; r++) {
                const float lv = ls[ib + r];
                const float inv = (lv > 0.f) ? 1.f / lv : 0.f;
#pragma unroll
                for (int nt = 0; nt < 4; nt++) {
                    float vv = acc[ip][nt][r] * inv;
                    vv = (vv > 0.f) ? vv : __expf(vv) - 1.f;   // elu
                    sl[jg * 4 + r][nt * 16 + fq] = vv;
                }
            }
            const unsigned g = (unsigned)b * 20 + (IP0 + ip) * 4 + w;
#pragma unroll
            for (int kth = 0; kth < 2; kth++) {
                float f[8];
                *(float4*)&f[0] = *(const float4*)&sl[fq][kth * 32 + jg * 8];
                *(float4*)&f[4] = *(const float4*)&sl[fq][kth * 32 + jg * 8 + 4];
                unsigned short h[8], l[8];
#pragma unroll
                for (int e = 0; e < 8; e++) split1(f[e], h[e], l[e]);
                const size_t o = (((size_t)g * 16 + ktg0 + kth) * 64 + lane) * 8;
                *(uint4*)&xhi_g[o] = make_uint4(pack2(h[0],h[1]), pack2(h[2],h[3]),
                                                pack2(h[4],h[5]), pack2(h[6],h[7]));
                *(uint4*)&xlo_g[o] = make_uint4(pack2(l[0],l[1]), pack2(l[2],l[3]),
                                                pack2(l[4],l[5]), pack2(l[6],l[7]));
            }
        }
    }
}

__global__ __launch_bounds__(256, 4) void attn_mfma(
    const unsigned short* __restrict__ Hthi, const unsigned short* __restrict__ Htlo,
    float* __restrict__ xout, int final_out)
{
    __shared__ float fjs[NN];
    __shared__ float ls[NN];
    __shared__ float slabA[4][16][68];
    if (blockIdx.y == 0) attn_body<0, 3>(Hthi, Htlo, xout, final_out, fjs, ls, slabA);
    else                 attn_body<3, 2>(Hthi, Htlo, xout, final_out, fjs, ls, slabA);
}

// ---------------------------------------------------------------------------
// Flow: build_me; presplit inputs (fragment layout); per matmul: presplit_B
// then gemm_reg. proj -> x planes; per layer: gemm_h -> Ht(ws)+fi/fj;
// attn -> x planes (l=0, elu) / fp32 d_out (l=1). Strictly stream-ordered.
// ---------------------------------------------------------------------------
extern "C" void kernel_launch(void* const* d_in, const int* in_sizes, int n_in,
                              void* d_out, int out_size, void* d_ws, size_t ws_size,
                              hipStream_t stream)
{
    (void)in_sizes; (void)n_in; (void)out_size; (void)ws_size;
    const float* text     = (const float*)d_in[0];
    const float* visual   = (const float*)d_in[1];
    const float* acoustic = (const float*)d_in[2];
    const int*   adj      = (const int*)d_in[3];
    const float* Wt       = (const float*)d_in[4];
    const float* Wv       = (const float*)d_in[5];
    const float* Wa       = (const float*)d_in[6];
    const float* Wg       = (const float*)d_in[7];
    const float* a_src    = (const float*)d_in[8];
    const float* a_dst    = (const float*)d_in[9];
    const float* elog     = (const float*)d_in[10];

    float* xbuf = (float*)d_out;
    unsigned short* Hthi = (unsigned short*)d_ws;
    unsigned short* Htlo = Hthi + (size_t)512 * 10 * 4 * 512;   // 10,485,760 shorts

    build_me<<<NN * NN / 1024, 256, 0, stream>>>(adj, elog);

    // inputs -> fragment planes: grid = M/16 * nk * 64 / 256
    presplit_A<<<(16384 / 16) * 24 * 64 / 256, 256, 0, stream>>>(text,     16384, 768, 24, 0);
    presplit_A<<<(2048  / 16) * 2  * 64 / 256, 256, 0, stream>>>(visual,   2048,  47,  2,  1);
    presplit_A<<<(2048  / 16) * 4  * 64 / 256, 256, 0, stream>>>(acoustic, 2048,  74,  4,  2);

    // projections -> x planes
    presplit_B<<<dim3(32, 768 / 32), 64, 0, stream>>>(Wt, 768, 768, 0);
    gemm_reg<<<dim3((BB*NT)/128, 4), 256, 0, stream>>>(nullptr, nullptr, nullptr, nullptr,
                                                       24, 0, 0, NT, 0);
    presplit_B<<<dim3(32, 64 / 32), 64, 0, stream>>>(Wv, 47, 64, 0);
    gemm_reg<<<dim3((BB*NV)/128, 4), 256, 0, stream>>>(nullptr, nullptr, nullptr, nullptr,
                                                       2, 1, 0, NV, NT);
    presplit_B<<<dim3(32, 128 / 32), 64, 0, stream>>>(Wa, 74, 128, 0);
    gemm_reg<<<dim3((BB*NA)/128, 4), 256, 0, stream>>>(nullptr, nullptr, nullptr, nullptr,
                                                       4, 2, 0, NA, NT + NV);

    for (int l = 0; l < 2; l++) {
        const float* Wg_l = Wg + (size_t)l * NHEAD * HIDD * FD;
        presplit_B<<<dim3(32, 512 / 32), 64, 0, stream>>>(Wg_l, 512, 512, 1);
        gemm_reg<<<dim3((BB*NN)/128, 4), 256, 0, stream>>>(Hthi, Htlo,
            a_src + l * NHEAD * FD, a_dst + l * NHEAD * FD, 16, 3, 1, NN, 0);
        attn_mfma<<<dim3(BB * NHEAD, 2), 256, 0, stream>>>(
            Hthi, Htlo, xbuf, (l == 0) ? 0 : 1);
    }
}

// Round 6
// 364.516 us; speedup vs baseline: 1.2586x; 1.0091x over previous
//
#include <hip/hip_runtime.h>
#include <hip/hip_bf16.h>
#include <math.h>

#define BB 64
#define NN 320
#define NT 256
#define NV 32
#define NA 32
#define HIDD 512
#define NHEAD 8
#define FD 64

typedef __attribute__((ext_vector_type(8))) short bf16x8;
typedef __attribute__((ext_vector_type(4))) float floatx4;

// ---------------------------------------------------------------------------
// device-global scratch (stream-ordered producer->consumer):
//   me_g   : adj-masked exp(edge_logits), built once
//   fif/fjf: per-(b,head) attention dot products, written by gemm_h epilogue
//   ti/vi/ac planes: presplit inputs, A-FRAGMENT layout [g][kt][lane][8]
//     (g = row/16, kt = k/32, lane = (row&15)|(((k>>3)&3)<<4), e = k&7)
//   x planes: node features between layers, same A-fragment layout (nk=16)
//   bw planes: current weight matrix, B-fragment layout [tg][kt][lane][8]
// Every load anywhere is lane-contiguous 16B. Ht lives in d_ws.
// ---------------------------------------------------------------------------
__device__ float me_g[NN * NN];
__device__ float fif_g[512 * NN];
__device__ float fjf_g[512 * NN];
__device__ unsigned short tihi_g[16384 * 768];
__device__ unsigned short tilo_g[16384 * 768];
__device__ unsigned short vihi_g[2048 * 64];
__device__ unsigned short vilo_g[2048 * 64];
__device__ unsigned short achi_g[2048 * 128];
__device__ unsigned short aclo_g[2048 * 128];
__device__ unsigned short xhi_g[20480 * 512];
__device__ unsigned short xlo_g[20480 * 512];
__device__ unsigned short bwhi_g[512 * 768];
__device__ unsigned short bwlo_g[512 * 768];

__device__ __forceinline__ void split1(float v, unsigned short& h, unsigned short& l) {
    unsigned u = __float_as_uint(v);
    unsigned hu = u & 0xFFFF0000u;
    float lf = v - __uint_as_float(hu);
    h = (unsigned short)(hu >> 16);
    l = (unsigned short)(__float_as_uint(lf) >> 16);
}
__device__ __forceinline__ unsigned pack2(unsigned short a, unsigned short b) {
    return (unsigned)a | ((unsigned)b << 16);
}

// async global->LDS 16B/lane: LDS dest = wave-uniform base + lane*16,
// global src = per-lane address. CK-style addrspace casts via uintptr.
typedef const __attribute__((address_space(1))) unsigned int* gas1_t;
typedef __attribute__((address_space(3))) unsigned int* las3_t;
__device__ __forceinline__ void gload_lds16(const void* g, void* s) {
    __builtin_amdgcn_global_load_lds((gas1_t)(unsigned long long)g,
                                     (las3_t)(unsigned)(unsigned long long)s,
                                     16, 0, 0);
}

// ---------------------------------------------------------------------------
// me = adj ? exp(elog) : 0
// ---------------------------------------------------------------------------
__global__ __launch_bounds__(256) void build_me(
    const int* __restrict__ adj, const float* __restrict__ elog)
{
    const int i4 = (blockIdx.x * 256 + threadIdx.x) * 4;
    const int4   a = *(const int4*)&adj[i4];
    const float4 e = *(const float4*)&elog[i4];
    float4 m;
    m.x = a.x ? __expf(e.x) : 0.f;
    m.y = a.y ? __expf(e.y) : 0.f;
    m.z = a.z ? __expf(e.z) : 0.f;
    m.w = a.w ? __expf(e.w) : 0.f;
    *(float4*)&me_g[i4] = m;
}

// ---------------------------------------------------------------------------
// presplit_A: fp32 [M][K] -> split-bf16 A-fragment planes [M/16][nk][64][8].
// ---------------------------------------------------------------------------
__global__ __launch_bounds__(256) void presplit_A(
    const float* __restrict__ src, int M, int K, int nk, int sel)
{
    unsigned short* dh = (sel == 0) ? tihi_g : (sel == 1) ? vihi_g : achi_g;
    unsigned short* dl = (sel == 0) ? tilo_g : (sel == 1) ? vilo_g : aclo_g;
    const unsigned t = blockIdx.x * 256 + threadIdx.x;
    const unsigned lane = t & 63, rec = t >> 6;
    const unsigned kt = rec % (unsigned)nk, g = rec / (unsigned)nk;
    const int row = g * 16 + (lane & 15);
    if (row >= M) return;
    const int k0 = kt * 32 + ((lane >> 4) << 3);
    float v[8];
    if (((K & 3) == 0) && (k0 + 8 <= K)) {
        *(float4*)&v[0] = *(const float4*)&src[(size_t)row * K + k0];
        *(float4*)&v[4] = *(const float4*)&src[(size_t)row * K + k0 + 4];
    } else {
#pragma unroll
        for (int e = 0; e < 8; e++) v[e] = (k0 + e < K) ? src[(size_t)row * K + k0 + e] : 0.f;
    }
    unsigned short h[8], l[8];
#pragma unroll
    for (int e = 0; e < 8; e++) split1(v[e], h[e], l[e]);
    const size_t o = (size_t)t * 8;
    *(uint4*)&dh[o] = make_uint4(pack2(h[0],h[1]), pack2(h[2],h[3]),
                                 pack2(h[4],h[5]), pack2(h[6],h[7]));
    *(uint4*)&dl[o] = make_uint4(pack2(l[0],l[1]), pack2(l[2],l[3]),
                                 pack2(l[4],l[5]), pack2(l[6],l[7]));
}

// ---------------------------------------------------------------------------
// presplit_B: weight fp32 -> split-bf16 B-fragment planes [tg][kt][64][8]:
//   col = tg*16+(lane&15), k = kt*32+(lane>>4)*8+e. Zero-pads k >= K.
// wg_mode 0: W row-major [K][512]. wg_mode 1: W = Wg_l [head][512][64].
// ---------------------------------------------------------------------------
__global__ __launch_bounds__(64) void presplit_B(
    const float* __restrict__ W, int K, int Kp, int wg_mode)
{
    const int lane = threadIdx.x;
    const int nt = blockIdx.x, kt = blockIdx.y;
    const int col = nt * 16 + (lane & 15);
    const int k0 = kt * 32 + (lane >> 4) * 8;
    unsigned short h[8], l[8];
#pragma unroll
    for (int e = 0; e < 8; e++) {
        const int k = k0 + e;
        float v = 0.f;
        if (k < K) v = wg_mode ? W[(size_t)(col >> 6) * (512 * 64) + (size_t)k * 64 + (col & 63)]
                               : W[(size_t)k * 512 + col];
        split1(v, h[e], l[e]);
    }
    const size_t o = (((size_t)nt * (Kp >> 5) + kt) * 64 + lane) * 8;
    *(uint4*)&bwhi_g[o] = make_uint4(pack2(h[0], h[1]), pack2(h[2], h[3]),
                                     pack2(h[4], h[5]), pack2(h[6], h[7]));
    *(uint4*)&bwlo_g[o] = make_uint4(pack2(l[0], l[1]), pack2(l[2], l[3]),
                                     pack2(l[4], l[5]), pack2(l[6], l[7]));
}

// ---------------------------------------------------------------------------
// gemm_lds (m97 structure): 128x128 tile, BK=32, 4 waves each 64x64, 3-pass
// split-bf16. Per kt the block stages 32 fragment-records (1KB each: Ahi x8,
// Alo x8, Bhi x8, Blo x8 -- wave w owns plane w, 8 global_load_lds) into a
// single 32KB LDS buffer with the canonical 2-barrier loop; frag reads are
// stride-1 ds_read_b128 (conflict-free). acc 64 + frag 64 regs ->
// __launch_bounds__(256,3) = 3 blocks/CU.
// b_mode 0: proj epilogue -> x fragment planes via per-wave LDS transpose
//           (reuses stage buffer after a barrier).
// b_mode 1: gemm_h -> Ht fragment epilogue + fi/fj fold.
// ---------------------------------------------------------------------------
#define GMFMA(AH, AL, BH, BL)                                                  \
  _Pragma("unroll") for (int s = 0; s < 4; s++)                                \
  _Pragma("unroll") for (int t = 0; t < 4; t++) {                              \
      acc[s][t] = __builtin_amdgcn_mfma_f32_16x16x32_bf16(AH[s], BH[t], acc[s][t], 0, 0, 0); \
      acc[s][t] = __builtin_amdgcn_mfma_f32_16x16x32_bf16(AH[s], BL[t], acc[s][t], 0, 0, 0); \
      acc[s][t] = __builtin_amdgcn_mfma_f32_16x16x32_bf16(AL[s], BH[t], acc[s][t], 0, 0, 0); }

__global__ __launch_bounds__(256, 3) void gemm_lds(
    unsigned short* __restrict__ Hthi, unsigned short* __restrict__ Htlo,
    const float* __restrict__ asrc, const float* __restrict__ adst,
    int nk, int a_sel, int b_mode, int rpb, int noff)
{
    __shared__ __align__(16) unsigned short stage[32 * 512];   // 32 KB

    const unsigned short* Ahi = (a_sel == 0) ? tihi_g : (a_sel == 1) ? vihi_g
                              : (a_sel == 2) ? achi_g : xhi_g;
    const unsigned short* Alo = (a_sel == 0) ? tilo_g : (a_sel == 1) ? vilo_g
                              : (a_sel == 2) ? aclo_g : xlo_g;

    const int tid = threadIdx.x, lane = tid & 63, w = tid >> 6;
    const int rw = w >> 1, cw = w & 1;
    const int m0 = blockIdx.x * 128, n0 = blockIdx.y * 128;
    const int g0 = m0 >> 4, tg0 = n0 >> 4;

    // staging: wave w owns one plane (0:Ahi 1:Alo 2:Bhi 3:Blo), 8 records
    const unsigned short* plane = (w == 0) ? Ahi : (w == 1) ? Alo
                                : (w == 2) ? bwhi_g : bwlo_g;
    const unsigned rec0 = (w < 2) ? (unsigned)g0 : (unsigned)tg0;
    const unsigned short* wsrc = plane + (size_t)rec0 * nk * 512 + lane * 8;
    unsigned short* wdst = &stage[(w * 8) * 512];

    floatx4 acc[4][4];
#pragma unroll
    for (int s = 0; s < 4; s++)
#pragma unroll
        for (int t = 0; t < 4; t++) acc[s][t] = (floatx4)0.f;

    for (int kt = 0; kt < nk; ++kt) {
        __syncthreads();   // previous iter's frag ds_reads done before overwrite
#pragma unroll
        for (int u = 0; u < 8; u++)
            gload_lds16(wsrc + ((size_t)u * nk + kt) * 512, wdst + u * 512);
        __syncthreads();   // drains vmcnt(0): all 32 records landed

        bf16x8 a_h[4], a_l[4], b_h[4], b_l[4];
#pragma unroll
        for (int s = 0; s < 4; s++) {
            a_h[s] = *(const bf16x8*)&stage[(rw * 4 + s) * 512 + lane * 8];
            a_l[s] = *(const bf16x8*)&stage[(8 + rw * 4 + s) * 512 + lane * 8];
        }
#pragma unroll
        for (int t = 0; t < 4; t++) {
            b_h[t] = *(const bf16x8*)&stage[(16 + cw * 4 + t) * 512 + lane * 8];
            b_l[t] = *(const bf16x8*)&stage[(24 + cw * 4 + t) * 512 + lane * 8];
        }
        GMFMA(a_h, a_l, b_h, b_l);
    }

    const int fq = lane & 15, rl = lane >> 4;

    if (b_mode == 0) {
        // ---- proj epilogue: D -> x fragment planes via LDS transpose ----
        __syncthreads();   // all waves done reading stage before slab reuse
        float (*sl)[68] = (float (*)[68])(&stage[w * 2176]);   // 16x68 fp32
        const int ktg0 = (n0 + cw * 64) >> 5;     // x k-tile base (x nk = 16)
#pragma unroll
        for (int s = 0; s < 4; s++) {
#pragma unroll
            for (int t = 0; t < 4; t++)
#pragma unroll
                for (int r = 0; r < 4; r++)
                    sl[rl * 4 + r][t * 16 + fq] = acc[s][t][r];
            const int grow16 = m0 + rw * 64 + s * 16;
            const int b = grow16 / rpb;
            const int rr = grow16 - b * rpb;
            const unsigned g = (unsigned)b * 20 + (unsigned)((noff + rr) >> 4);
#pragma unroll
            for (int kth = 0; kth < 2; kth++) {
                float f[8];
                *(float4*)&f[0] = *(const float4*)&sl[fq][kth * 32 + rl * 8];
                *(float4*)&f[4] = *(const float4*)&sl[fq][kth * 32 + rl * 8 + 4];
                unsigned short h[8], l[8];
#pragma unroll
                for (int e = 0; e < 8; e++) split1(f[e], h[e], l[e]);
                const size_t o = (((size_t)g * 16 + ktg0 + kth) * 64 + lane) * 8;
                *(uint4*)&xhi_g[o] = make_uint4(pack2(h[0],h[1]), pack2(h[2],h[3]),
                                                pack2(h[4],h[5]), pack2(h[6],h[7]));
                *(uint4*)&xlo_g[o] = make_uint4(pack2(l[0],l[1]), pack2(l[2],l[3]),
                                                pack2(l[4],l[5]), pack2(l[6],l[7]));
            }
        }
    } else {
        // ---- Ht fragment-layout split-bf16 epilogue ----
        const int hd = (n0 + cw * 64) >> 6;
#pragma unroll
        for (int s = 0; s < 4; s++) {
            const int m_s = m0 + rw * 64 + s * 16 + rl * 4;   // rows m_s..m_s+3
            const unsigned b = (unsigned)m_s / 320u;
            const int jb = m_s - b * 320;
            const int ks = jb >> 5;
            const int jg2 = (jb >> 3) & 3;
            const int eb = jb & 7;
            const size_t slabo = (size_t)b * 8 + hd;
#pragma unroll
            for (int t = 0; t < 4; t++) {
                unsigned short h0,h1,h2,h3,l0,l1,l2,l3;
                split1(acc[s][t][0],h0,l0); split1(acc[s][t][1],h1,l1);
                split1(acc[s][t][2],h2,l2); split1(acc[s][t][3],h3,l3);
                const size_t base = (((slabo * 10 + ks) * 4 + t) * 512
                                     + (size_t)(fq | (jg2 << 4)) * 8) + eb;
                *(uint2*)&Hthi[base] = make_uint2(pack2(h0,h1), pack2(h2,h3));
                *(uint2*)&Htlo[base] = make_uint2(pack2(l0,l1), pack2(l2,l3));
            }
        }
        // fi/fj fold: exact fp32 dot(H_row, a_src/a_dst) per (row, head)
        float as4[4], ad4[4];
#pragma unroll
        for (int t = 0; t < 4; t++) {
            as4[t] = asrc[hd * 64 + t * 16 + fq];
            ad4[t] = adst[hd * 64 + t * 16 + fq];
        }
#pragma unroll
        for (int s = 0; s < 4; s++) {
            const int m_s = m0 + rw * 64 + s * 16 + rl * 4;
            const unsigned b = (unsigned)m_s / 320u;
            const int jb = m_s - b * 320;
            float4 fi4, fj4;
#pragma unroll
            for (int r = 0; r < 4; r++) {
                float fi = (acc[s][0][r]*as4[0] + acc[s][1][r]*as4[1])
                         + (acc[s][2][r]*as4[2] + acc[s][3][r]*as4[3]);
                float fj = (acc[s][0][r]*ad4[0] + acc[s][1][r]*ad4[1])
                         + (acc[s][2][r]*ad4[2] + acc[s][3][r]*ad4[3]);
#pragma unroll
                for (int d = 1; d < 16; d <<= 1) {
                    fi += __shfl_xor(fi, d);
                    fj += __shfl_xor(fj, d);
                }
                ((float*)&fi4)[r] = fi; ((float*)&fj4)[r] = fj;
            }
            if (fq == 0) {
                const size_t o = ((size_t)b * 8 + hd) * NN + jb;
                *(float4*)&fif_g[o] = fi4;
                *(float4*)&fjf_g[o] = fj4;
            }
        }
    }
}

// ---------------------------------------------------------------------------
// MFMA GAT attention (v4 structure): grid (512, 2), 4 blocks/CU.
// final_out=0 (layer 0): elu, write x fragment planes via LDS transpose.
// final_out=1 (layer 1): write fp32 to d_out.
// ---------------------------------------------------------------------------
template<int IP0, int NIP>
__device__ __forceinline__ void attn_body(
    const unsigned short* __restrict__ Hthi, const unsigned short* __restrict__ Htlo,
    float* __restrict__ xout, int final_out, float* fjs, float* ls,
    float (*slabA)[16][68])
{
    const int bh = blockIdx.x;          // b*8 + hd
    const int hd = bh & 7, b = bh >> 3;
    const int tid = threadIdx.x, lane = tid & 63, w = tid >> 6;
    const int fq = lane & 15, jg = lane >> 4;

    for (int r = tid; r < NN; r += 256) fjs[r] = fjf_g[bh * NN + r];

    float fir[NIP];
#pragma unroll
    for (int ip = 0; ip < NIP; ip++)
        fir[ip] = fif_g[bh * NN + (IP0 + ip) * 64 + (w << 4) + fq];
    __syncthreads();

    floatx4 acc[NIP][4];
#pragma unroll
    for (int ip = 0; ip < NIP; ip++)
#pragma unroll
        for (int nt = 0; nt < 4; nt++) acc[ip][nt] = (floatx4)0.f;
    float lacc[NIP];
#pragma unroll
    for (int ip = 0; ip < NIP; ip++) lacc[ip] = 0.f;

    for (int ks = 0; ks < 10; ks++) {
        const int j8 = ks * 32 + jg * 8;
        const float4 fj0 = *(const float4*)&fjs[j8];
        const float4 fj1 = *(const float4*)&fjs[j8 + 4];

        // ---- phase 1: scores -> exp*me -> split-bf16 A-frags ----
        bf16x8 ahh[NIP], all[NIP];
#pragma unroll
        for (int ip = 0; ip < NIP; ip++) {
            const int i = (IP0 + ip) * 64 + (w << 4) + fq;
            const float fiv = fir[ip];
            const unsigned g = (unsigned)i * NN + j8;
            const float4 m0 = *(const float4*)&me_g[g];
            const float4 m1 = *(const float4*)&me_g[g + 4];
            float p[8];
            {
                float s;
                s = fiv + fj0.x; s = fmaxf(s, 0.2f*s); p[0] = __expf(s) * m0.x;
                s = fiv + fj0.y; s = fmaxf(s, 0.2f*s); p[1] = __expf(s) * m0.y;
                s = fiv + fj0.z; s = fmaxf(s, 0.2f*s); p[2] = __expf(s) * m0.z;
                s = fiv + fj0.w; s = fmaxf(s, 0.2f*s); p[3] = __expf(s) * m0.w;
                s = fiv + fj1.x; s = fmaxf(s, 0.2f*s); p[4] = __expf(s) * m1.x;
                s = fiv + fj1.y; s = fmaxf(s, 0.2f*s); p[5] = __expf(s) * m1.y;
                s = fiv + fj1.z; s = fmaxf(s, 0.2f*s); p[6] = __expf(s) * m1.z;
                s = fiv + fj1.w; s = fmaxf(s, 0.2f*s); p[7] = __expf(s) * m1.w;
            }
            lacc[ip] += ((p[0]+p[1]) + (p[2]+p[3])) + ((p[4]+p[5]) + (p[6]+p[7]));

            unsigned short ph[8], pl[8];
#pragma unroll
            for (int e = 0; e < 8; e++) split1(p[e], ph[e], pl[e]);
            union { uint4 u; bf16x8 v; } ua, ul;
            ua.u = make_uint4(pack2(ph[0],ph[1]), pack2(ph[2],ph[3]),
                              pack2(ph[4],ph[5]), pack2(ph[6],ph[7]));
            ul.u = make_uint4(pack2(pl[0],pl[1]), pack2(pl[2],pl[3]),
                              pack2(pl[4],pl[5]), pack2(pl[6],pl[7]));
            ahh[ip] = ua.v; all[ip] = ul.v;
        }

        // ---- phase 2: per f-tile, load B pair then 3*NIP MFMAs ----
#pragma unroll
        for (int nt = 0; nt < 4; nt++) {
            const unsigned off = (((unsigned)bh * 10 + ks) * 4 + nt) * 512 + (unsigned)lane * 8;
            const bf16x8 bhf = *(const bf16x8*)&Hthi[off];
            const bf16x8 blf = *(const bf16x8*)&Htlo[off];
#pragma unroll
            for (int ip = 0; ip < NIP; ip++) {
                acc[ip][nt] = __builtin_amdgcn_mfma_f32_16x16x32_bf16(ahh[ip], bhf, acc[ip][nt], 0, 0, 0);
                acc[ip][nt] = __builtin_amdgcn_mfma_f32_16x16x32_bf16(ahh[ip], blf, acc[ip][nt], 0, 0, 0);
                acc[ip][nt] = __builtin_amdgcn_mfma_f32_16x16x32_bf16(all[ip], bhf, acc[ip][nt], 0, 0, 0);
            }
        }
    }

    // ---- l reduction: sum over the 4 jg lanes holding the same i ----
#pragma unroll
    for (int ip = 0; ip < NIP; ip++) {
        float l = lacc[ip];
        l += __shfl_xor(l, 16);
        l += __shfl_xor(l, 32);
        if (jg == 0) ls[(IP0 + ip) * 64 + (w << 4) + fq] = l;
    }
    __syncthreads();

    // ---- epilogue: D col(f)=fq, row(i)=jg*4+r ----
    if (final_out) {
#pragma unroll
        for (int ip = 0; ip < NIP; ip++) {
            const int ib = ((IP0 + ip) * 4 + w) * 16 + jg * 4;
#pragma unroll
            for (int r = 0; r < 4; r++) {
                const float lv = ls[ib + r];
                const float inv = (lv > 0.f) ? 1.f / lv : 0.f;
                const size_t ro = ((size_t)(b * NN + ib + r)) * HIDD + hd * 64;
#pragma unroll
                for (int nt = 0; nt < 4; nt++)
                    xout[ro + nt * 16 + fq] = acc[ip][nt][r] * inv;
            }
        }
    } else {
        // elu + write x fragment planes via per-wave LDS transpose
        float (*sl)[68] = slabA[w];
        const int ktg0 = hd * 2;
#pragma unroll
        for (int ip = 0; ip < NIP; ip++) {
            const int ib = ((IP0 + ip) * 4 + w) * 16 + jg * 4;
#pragma unroll
            for (int r = 0; r < 4; r++) {
                const float lv = ls[ib + r];
                const float inv = (lv > 0.f) ? 1.f / lv : 0.f;
#pragma unroll
                for (int nt = 0; nt < 4; nt++) {
                    float vv = acc[ip][nt][r] * inv;
                    vv = (vv > 0.f) ? vv : __expf(vv) - 1.f;   // elu
                    sl[jg * 4 + r][nt * 16 + fq] = vv;
                }
            }
            const unsigned g = (unsigned)b * 20 + (IP0 + ip) * 4 + w;
#pragma unroll
            for (int kth = 0; kth < 2; kth++) {
                float f[8];
                *(float4*)&f[0] = *(const float4*)&sl[fq][kth * 32 + jg * 8];
                *(float4*)&f[4] = *(const float4*)&sl[fq][kth * 32 + jg * 8 + 4];
                unsigned short h[8], l[8];
#pragma unroll
                for (int e = 0; e < 8; e++) split1(f[e], h[e], l[e]);
                const size_t o = (((size_t)g * 16 + ktg0 + kth) * 64 + lane) * 8;
                *(uint4*)&xhi_g[o] = make_uint4(pack2(h[0],h[1]), pack2(h[2],h[3]),
                                                pack2(h[4],h[5]), pack2(h[6],h[7]));
                *(uint4*)&xlo_g[o] = make_uint4(pack2(l[0],l[1]), pack2(l[2],l[3]),
                                                pack2(l[4],l[5]), pack2(l[6],l[7]));
            }
        }
    }
}

__global__ __launch_bounds__(256, 4) void attn_mfma(
    const unsigned short* __restrict__ Hthi, const unsigned short* __restrict__ Htlo,
    float* __restrict__ xout, int final_out)
{
    __shared__ float fjs[NN];
    __shared__ float ls[NN];
    __shared__ float slabA[4][16][68];
    if (blockIdx.y == 0) attn_body<0, 3>(Hthi, Htlo, xout, final_out, fjs, ls, slabA);
    else                 attn_body<3, 2>(Hthi, Htlo, xout, final_out, fjs, ls, slabA);
}

// ---------------------------------------------------------------------------
// Flow: build_me; presplit inputs (fragment layout); per matmul: presplit_B
// then gemm_lds. proj -> x planes; per layer: gemm_h -> Ht(ws)+fi/fj;
// attn -> x planes (l=0, elu) / fp32 d_out (l=1). Strictly stream-ordered.
// ---------------------------------------------------------------------------
extern "C" void kernel_launch(void* const* d_in, const int* in_sizes, int n_in,
                              void* d_out, int out_size, void* d_ws, size_t ws_size,
                              hipStream_t stream)
{
    (void)in_sizes; (void)n_in; (void)out_size; (void)ws_size;
    const float* text     = (const float*)d_in[0];
    const float* visual   = (const float*)d_in[1];
    const float* acoustic = (const float*)d_in[2];
    const int*   adj      = (const int*)d_in[3];
    const float* Wt       = (const float*)d_in[4];
    const float* Wv       = (const float*)d_in[5];
    const float* Wa       = (const float*)d_in[6];
    const float* Wg       = (const float*)d_in[7];
    const float* a_src    = (const float*)d_in[8];
    const float* a_dst    = (const float*)d_in[9];
    const float* elog     = (const float*)d_in[10];

    float* xbuf = (float*)d_out;
    unsigned short* Hthi = (unsigned short*)d_ws;
    unsigned short* Htlo = Hthi + (size_t)512 * 10 * 4 * 512;   // 10,485,760 shorts

    build_me<<<NN * NN / 1024, 256, 0, stream>>>(adj, elog);

    // inputs -> fragment planes: grid = M/16 * nk * 64 / 256
    presplit_A<<<(16384 / 16) * 24 * 64 / 256, 256, 0, stream>>>(text,     16384, 768, 24, 0);
    presplit_A<<<(2048  / 16) * 2  * 64 / 256, 256, 0, stream>>>(visual,   2048,  47,  2,  1);
    presplit_A<<<(2048  / 16) * 4  * 64 / 256, 256, 0, stream>>>(acoustic, 2048,  74,  4,  2);

    // projections -> x planes
    presplit_B<<<dim3(32, 768 / 32), 64, 0, stream>>>(Wt, 768, 768, 0);
    gemm_lds<<<dim3((BB*NT)/128, 4), 256, 0, stream>>>(nullptr, nullptr, nullptr, nullptr,
                                                       24, 0, 0, NT, 0);
    presplit_B<<<dim3(32, 64 / 32), 64, 0, stream>>>(Wv, 47, 64, 0);
    gemm_lds<<<dim3((BB*NV)/128, 4), 256, 0, stream>>>(nullptr, nullptr, nullptr, nullptr,
                                                       2, 1, 0, NV, NT);
    presplit_B<<<dim3(32, 128 / 32), 64, 0, stream>>>(Wa, 74, 128, 0);
    gemm_lds<<<dim3((BB*NA)/128, 4), 256, 0, stream>>>(nullptr, nullptr, nullptr, nullptr,
                                                       4, 2, 0, NA, NT + NV);

    for (int l = 0; l < 2; l++) {
        const float* Wg_l = Wg + (size_t)l * NHEAD * HIDD * FD;
        presplit_B<<<dim3(32, 512 / 32), 64, 0, stream>>>(Wg_l, 512, 512, 1);
        gemm_lds<<<dim3((BB*NN)/128, 4), 256, 0, stream>>>(Hthi, Htlo,
            a_src + l * NHEAD * FD, a_dst + l * NHEAD * FD, 16, 3, 1, NN, 0);
        attn_mfma<<<dim3(BB * NHEAD, 2), 256, 0, stream>>>(
            Hthi, Htlo, xbuf, (l == 0) ? 0 : 1);
    }
}